// Round 2
// baseline (405.601 us; speedup 1.0000x reference)
//
#include <hip/hip_runtime.h>
#include <stdint.h>

#define BB 64
#define CC 256
#define HH 56
#define WW 56
#define HWN 3136          // 56*56
#define NCH (BB*CC)       // 16384
#define TOPK 38
#define NV4 784           // HWN / 4 float4 per channel
#define DD 16             // hidden dim

// ---------------- Pass A: per-channel sum (fp64) + argmax (first-index tie-break) ----
__global__ __launch_bounds__(256) void reduce_kernel(const float* __restrict__ x,
                                                     double* __restrict__ sums,
                                                     int* __restrict__ amax) {
    const int wave = threadIdx.x >> 6;
    const int lane = threadIdx.x & 63;
    const int ch = blockIdx.x * 4 + wave;              // flat (b,c)
    const float4* p = (const float4*)(x + (size_t)ch * HWN);

    double s = 0.0;
    float bv = -INFINITY; int bi = 0x7fffffff;
    for (int i = lane; i < NV4; i += 64) {
        float4 q = p[i];
        float f[4] = {q.x, q.y, q.z, q.w};
        const int e0 = i * 4;
        #pragma unroll
        for (int j = 0; j < 4; ++j) {
            s += (double)f[j];
            const int ij = e0 + j;
            if (f[j] > bv || (f[j] == bv && ij < bi)) { bv = f[j]; bi = ij; }
        }
    }
    // wave-64 reduction; only lane 0's result is used
    for (int off = 32; off >= 1; off >>= 1) {
        s += __shfl_down(s, off, 64);
        float ov = __shfl_down(bv, off, 64);
        int   oi = __shfl_down(bi, off, 64);
        if (ov > bv || (ov == bv && oi < bi)) { bv = ov; bi = oi; }
    }
    if (lane == 0) { sums[ch] = s; amax[ch] = bi; }
}

// ---------------- Pass B: SE module + top-k mask + box/lambda descriptor -------------
__global__ __launch_bounds__(256) void mask_kernel(const double* __restrict__ sums,
                                                   const int* __restrict__ amax,
                                                   const float* __restrict__ w1,
                                                   const float* __restrict__ w2,
                                                   float* __restrict__ lam_out,
                                                   uint32_t* __restrict__ box_out) {
    const int b = blockIdx.x;
    const int c = threadIdx.x;
    __shared__ double pooled[CC];
    __shared__ double hidden[DD];
    __shared__ double Ms[CC];

    pooled[c] = sums[b * CC + c] / (double)HWN;
    __syncthreads();

    if (c < DD) {
        double acc = 0.0;
        for (int j = 0; j < CC; ++j) acc += pooled[j] * (double)w1[c * CC + j];
        hidden[c] = acc > 0.0 ? acc : 0.0;             // relu
    }
    __syncthreads();

    double acc = 0.0;
    for (int d = 0; d < DD; ++d) acc += hidden[d] * (double)w2[c * DD + d];
    double m = 1.0 / (1.0 + exp(-acc));                // sigmoid
    Ms[c] = m;
    __syncthreads();

    // rank with jax top_k tie-break (lower index first among equals)
    int rank = 0;
    for (int j = 0; j < CC; ++j) {
        double mj = Ms[j];
        rank += (mj > m || (mj == m && j < c)) ? 1 : 0;
    }
    const bool sel = rank < TOPK;

    const int idx = amax[b * CC + c];
    const int mh = idx / WW, mw = idx - (idx / WW) * WW;
    const int h1 = mh - 2 > 0 ? mh - 2 : 0;
    const int h2 = mh + 2 < HH - 1 ? mh + 2 : HH - 1;
    const int w1b = mw - 2 > 0 ? mw - 2 : 0;
    const int w2b = mw + 2 < WW - 1 ? mw + 2 : WW - 1;
    const int area = (h2 - h1 + 1) * (w2b - w1b + 1);

    lam_out[b * CC + c] = sel ? (float)HWN / (float)(HWN - area) : 1.0f;
    // empty box (h1=255 > h2=0) when unselected -> pure passthrough
    box_out[b * CC + c] = sel
        ? (uint32_t)(h1 | (h2 << 8) | (w1b << 16) | (w2b << 24))
        : 0xFFu;
}

// ---------------- Pass C: apply scale / zero-box; lam=1 & empty box => bit-exact -----
__global__ __launch_bounds__(256) void apply_kernel(const float* __restrict__ x,
                                                    float* __restrict__ out,
                                                    const float* __restrict__ lam_arr,
                                                    const uint32_t* __restrict__ box_arr) {
    const int wave = threadIdx.x >> 6;
    const int lane = threadIdx.x & 63;
    const int ch = blockIdx.x * 4 + wave;

    const float lam = lam_arr[ch];
    const uint32_t box = box_arr[ch];
    const int h1 = box & 0xff, h2 = (box >> 8) & 0xff;
    const int w1b = (box >> 16) & 0xff, w2b = (box >> 24) & 0xff;

    const float4* p = (const float4*)(x + (size_t)ch * HWN);
    float4* q = (float4*)(out + (size_t)ch * HWN);

    for (int i = lane; i < NV4; i += 64) {
        float4 v = p[i];
        const int row = i / 14;                // 14 float4 per 56-wide row; never crosses
        const int cb = (i - row * 14) * 4;     // base column
        const bool inrow = (row >= h1) && (row <= h2);
        float f[4] = {v.x, v.y, v.z, v.w};
        #pragma unroll
        for (int j = 0; j < 4; ++j) {
            const int cj = cb + j;
            f[j] *= lam;                       // lam==1.0f -> exact
            if (inrow && cj >= w1b && cj <= w2b) f[j] = 0.0f;
        }
        float4 o; o.x = f[0]; o.y = f[1]; o.z = f[2]; o.w = f[3];
        q[i] = o;
    }
}

extern "C" void kernel_launch(void* const* d_in, const int* in_sizes, int n_in,
                              void* d_out, int out_size, void* d_ws, size_t ws_size,
                              hipStream_t stream) {
    const float* x  = (const float*)d_in[0];   // [64,256,56,56] f32
    const float* w1 = (const float*)d_in[1];   // [16,256] f32
    const float* w2 = (const float*)d_in[2];   // [256,16] f32
    float* out = (float*)d_out;                // [64,256,56,56] f32

    char* ws = (char*)d_ws;
    double*   sums = (double*)(ws);                  // 16384 * 8  = 128 KB
    int*      amax = (int*)(ws + 131072);            // 16384 * 4  =  64 KB
    float*    lam  = (float*)(ws + 196608);          // 16384 * 4  =  64 KB
    uint32_t* box  = (uint32_t*)(ws + 262144);       // 16384 * 4  =  64 KB

    reduce_kernel<<<NCH / 4, 256, 0, stream>>>(x, sums, amax);
    mask_kernel<<<BB, 256, 0, stream>>>(sums, amax, w1, w2, lam, box);
    apply_kernel<<<NCH / 4, 256, 0, stream>>>(x, out, lam, box);
}